// Round 10
// baseline (87.342 us; speedup 1.0000x reference)
//
#include <hip/hip_runtime.h>
#include <hip/hip_bf16.h>
#include <math.h>

#define DIN 512
#define TT  512

using bf16x8 = __attribute__((ext_vector_type(8))) short;
using f32x4  = __attribute__((ext_vector_type(4))) float;

static __device__ __forceinline__ unsigned short f2bf(float x) {
    __hip_bfloat16 h = __float2bfloat16(x);
    return *reinterpret_cast<unsigned short*>(&h);
}
static __device__ __forceinline__ unsigned int pack2(float a, float b) {
    return (unsigned int)f2bf(a) | ((unsigned int)f2bf(b) << 16);
}

// ws layout: Pgb bf16 [4][32][512] (128 KB), qb f32[128], flags int[128],
// part f32 [512][32][64] (4 MB). P/qb pre-scaled by 0.125.

__global__ __launch_bounds__(512) void pk_kernel(const float* __restrict__ Q,
                                                 const float* __restrict__ Wk,
                                                 const float* __restrict__ bk,
                                                 unsigned short* __restrict__ Pgb,
                                                 float* __restrict__ qb,
                                                 int* __restrict__ flags) {
    const int bid = blockIdx.x;   // [0,128) = bg*32 + p
    const int bg = bid >> 5;
    const int p  = bid & 31;
    const int h  = p >> 2;
    const int ua = p & 3;
    const int a_q = h >> 1;
    const int h_q = (4 * h + bg) & 7;
    const int ch_base = ua * 512 + h * 64;

    __shared__ float qv[64];
    const int tid = threadIdx.x;
    if (tid < 64) qv[tid] = Q[(a_q * 8 + h_q) * 64 + tid];
    if (tid == 0) flags[bid] = 0;          // re-init sync state every call
    __syncthreads();

    const int s = tid;
    float acc = 0.f;
    #pragma unroll 8
    for (int d = 0; d < 64; ++d)
        acc += qv[d] * Wk[(size_t)(ch_base + d) * DIN + s];
    Pgb[(size_t)(bg * 32 + p) * 512 + s] = f2bf(acc * 0.125f);

    if (tid == 0) {
        float sum = 0.f;
        for (int d = 0; d < 64; ++d) sum += qv[d] * bk[ch_base + d];
        qb[bg * 32 + p] = sum * 0.125f;
    }
}

// One block per (b, j).
// Phase A: scores[128 trow][32 p] = V[128x512] @ P^T via bf16 MFMA (r4 path), attn f32 out.
// Sync: release-add flags[b]; short sibling wait (flags[b]==4).
// Phase B: partial PV over v rows [j*128,(j+1)*128) (L3-hot, streamed in phase A)
//          for all 32 x-rows of batch b, using sibling attn slices. -> part scratch.
__global__ __launch_bounds__(256) void fused_kernel(const float* __restrict__ v,
                                                    const unsigned short* __restrict__ Pgb,
                                                    const float* __restrict__ qb,
                                                    float* __restrict__ attn,
                                                    float* __restrict__ part,
                                                    int* __restrict__ flags) {
    const int bid = blockIdx.x;   // b*4 + j
    const int b = bid >> 2;
    const int j = bid & 3;
    const int bg = b >> 5;
    const int tid = threadIdx.x;
    const int lane = tid & 63;
    const int w = tid >> 6;       // wave id: M rows w*32..w*32+31

    __shared__ __align__(16) char smem[43776];
    char* VtB = smem;                         // [128 rows][32 k] bf16, 80 B stride
    char* PtB = smem + 10240;                 // [32 p][512 k] bf16, 1040 B stride
    float (*red2)[2][4][2] = reinterpret_cast<float (*)[2][4][2]>(smem + 43520);

    const float* vbase = v + ((size_t)b * TT + j * 128) * DIN;

    {   // stage full P (bf16) once: 32 KB
        const int p  = tid >> 3;
        const int sg = tid & 7;
        const uint4* src = (const uint4*)(Pgb + ((size_t)(bg * 32 + p) * 512)) + sg * 8;
        uint4* dst = (uint4*)(PtB + p * 1040 + sg * 128);
        #pragma unroll
        for (int q = 0; q < 8; ++q) dst[q] = src[q];
    }

    const float qv0 = qb[bg * 32 + (lane & 15)];
    const float qv1 = qb[bg * 32 + 16 + (lane & 15)];

    f32x4 acc[2][2];
    #pragma unroll
    for (int i = 0; i < 2; ++i)
        #pragma unroll
        for (int n = 0; n < 2; ++n)
            #pragma unroll
            for (int r = 0; r < 4; ++r) acc[i][n][r] = 0.f;

    const int srow  = tid >> 1;
    const int shalf = tid & 1;
    const float* vsrc = vbase + (size_t)srow * DIN + shalf * 16;
    char* vdst = VtB + srow * 80 + shalf * 32;

    const int akb = (lane >> 4) * 16;
    const char* aptr  = VtB + (w * 32 + (lane & 15)) * 80 + akb;
    const char* bptr0 = PtB + ((lane & 15)) * 1040 + akb;
    const char* bptr1 = PtB + (16 + (lane & 15)) * 1040 + akb;

    float4 vrA[4], vrB[4];
    #pragma unroll
    for (int q = 0; q < 4; ++q) vrA[q] = *(const float4*)(vsrc + q * 4);
    #pragma unroll
    for (int q = 0; q < 4; ++q) vrB[q] = *(const float4*)(vsrc + 32 + q * 4);

#define SCORE_STEP(VR, KT)                                                    \
    {                                                                         \
        uint4 lo, hi;                                                         \
        lo.x = pack2(VR[0].x, VR[0].y); lo.y = pack2(VR[0].z, VR[0].w);       \
        lo.z = pack2(VR[1].x, VR[1].y); lo.w = pack2(VR[1].z, VR[1].w);       \
        hi.x = pack2(VR[2].x, VR[2].y); hi.y = pack2(VR[2].z, VR[2].w);       \
        hi.z = pack2(VR[3].x, VR[3].y); hi.w = pack2(VR[3].z, VR[3].w);       \
        *(uint4*)(vdst)      = lo;                                            \
        *(uint4*)(vdst + 16) = hi;                                            \
        __syncthreads();                                                      \
        if ((KT) < 14) {                                                      \
            const float* vn = vsrc + ((KT) + 2) * 32;                         \
            VR[0] = *(const float4*)(vn);                                     \
            VR[1] = *(const float4*)(vn + 4);                                 \
            VR[2] = *(const float4*)(vn + 8);                                 \
            VR[3] = *(const float4*)(vn + 12);                                \
        }                                                                     \
        const int ksb = (KT) * 64;                                            \
        bf16x8 a0 = *(const bf16x8*)(aptr);                                   \
        bf16x8 a1 = *(const bf16x8*)(aptr + 16 * 80);                         \
        bf16x8 b0 = *(const bf16x8*)(bptr0 + ksb);                            \
        bf16x8 b1 = *(const bf16x8*)(bptr1 + ksb);                            \
        acc[0][0] = __builtin_amdgcn_mfma_f32_16x16x32_bf16(a0, b0, acc[0][0], 0, 0, 0); \
        acc[0][1] = __builtin_amdgcn_mfma_f32_16x16x32_bf16(a0, b1, acc[0][1], 0, 0, 0); \
        acc[1][0] = __builtin_amdgcn_mfma_f32_16x16x32_bf16(a1, b0, acc[1][0], 0, 0, 0); \
        acc[1][1] = __builtin_amdgcn_mfma_f32_16x16x32_bf16(a1, b1, acc[1][1], 0, 0, 0); \
        __syncthreads();                                                      \
    }

    for (int kt = 0; kt < 16; kt += 2) {
        SCORE_STEP(vrA, kt);
        SCORE_STEP(vrB, kt + 1);
    }
#undef SCORE_STEP

    // ---- logits + per-h softmax ----
    float lg[2][8];
    #pragma unroll
    for (int i = 0; i < 2; ++i)
        #pragma unroll
        for (int r = 0; r < 4; ++r) {
            lg[0][i * 4 + r] = acc[i][0][r] + qv0;
            lg[1][i * 4 + r] = acc[i][1][r] + qv1;
        }

    const int hsub = (lane >> 2) & 3;
    float mw[2], sw[2], ev[2][8];
    #pragma unroll
    for (int nt = 0; nt < 2; ++nt) {
        float m = lg[nt][0];
        #pragma unroll
        for (int q = 1; q < 8; ++q) m = fmaxf(m, lg[nt][q]);
        m = fmaxf(m, __shfl_xor(m, 1));
        m = fmaxf(m, __shfl_xor(m, 2));
        m = fmaxf(m, __shfl_xor(m, 16));
        m = fmaxf(m, __shfl_xor(m, 32));
        float s = 0.f;
        #pragma unroll
        for (int q = 0; q < 8; ++q) { ev[nt][q] = __expf(lg[nt][q] - m); s += ev[nt][q]; }
        s += __shfl_xor(s, 1);
        s += __shfl_xor(s, 2);
        s += __shfl_xor(s, 16);
        s += __shfl_xor(s, 32);
        mw[nt] = m; sw[nt] = s;
    }
    if ((lane & 0x33) == 0) {
        #pragma unroll
        for (int nt = 0; nt < 2; ++nt) {
            red2[w][nt][hsub][0] = mw[nt];
            red2[w][nt][hsub][1] = sw[nt];
        }
    }
    __syncthreads();

    #pragma unroll
    for (int nt = 0; nt < 2; ++nt) {
        float M = red2[0][nt][hsub][0];
        M = fmaxf(M, red2[1][nt][hsub][0]);
        M = fmaxf(M, red2[2][nt][hsub][0]);
        M = fmaxf(M, red2[3][nt][hsub][0]);
        float S = 0.f;
        #pragma unroll
        for (int w2 = 0; w2 < 4; ++w2)
            S += __expf(red2[w2][nt][hsub][0] - M) * red2[w2][nt][hsub][1];
        const float factor = __expf(mw[nt] - M) / S;

        const int h = nt * 4 + hsub;
        float* arow = attn + ((size_t)(h * 512 + b * 4 + j)) * 512;
        const int ua = lane & 3;
        #pragma unroll
        for (int i = 0; i < 2; ++i)
            #pragma unroll
            for (int r = 0; r < 4; ++r) {
                const int trow = w * 32 + i * 16 + ((lane >> 4) & 3) * 4 + r;
                arow[trow * 4 + ua] = ev[nt][i * 4 + r] * factor;
            }
    }

    // ---- sync with the 3 sibling blocks of this batch ----
    __syncthreads();   // all waves' attn stores drained (barrier implies vmcnt(0))
    if (tid == 0) {
        __hip_atomic_fetch_add(flags + b, 1, __ATOMIC_RELEASE, __HIP_MEMORY_SCOPE_AGENT);
        while (__hip_atomic_load(flags + b, __ATOMIC_ACQUIRE, __HIP_MEMORY_SCOPE_AGENT) < 4)
            __builtin_amdgcn_s_sleep(16);
    }
    __syncthreads();

    // ---- phase B: partial PV over u in [j*128, (j+1)*128) ----
    // stage attn slices: at32[rh = h*4 + jp][u 0..128)
    float (*at32)[132] = reinterpret_cast<float (*)[132]>(smem);   // 16.9 KB
    {
        const int rh = tid >> 3;          // [0,32)
        const int g  = tid & 7;           // 16 floats each
        const int hh = rh >> 2;
        const int jp = rh & 3;
        const float* src = attn + ((size_t)(hh * 512 + b * 4 + jp)) * 512 + j * 128 + g * 16;
        #pragma unroll
        for (int q = 0; q < 4; ++q) {
            float4 t4 = *(const float4*)(src + q * 4);
            *(float4*)&at32[rh][g * 16 + q * 4] = t4;
        }
    }
    __syncthreads();

    const int hB = tid >> 5;              // [0,8)
    const int cp = tid & 31;              // channels hB*64 + cp*2 + {0,1}
    const float* vrow = v + ((size_t)b * TT + j * 128) * DIN + hB * 64 + cp * 2;
    const int h4 = hB * 4;

    float accB[4][2];
    #pragma unroll
    for (int jp = 0; jp < 4; ++jp) { accB[jp][0] = 0.f; accB[jp][1] = 0.f; }

    for (int u4 = 0; u4 < 32; ++u4) {
        const float4 a0 = *(const float4*)&at32[h4 + 0][u4 * 4];
        const float4 a1 = *(const float4*)&at32[h4 + 1][u4 * 4];
        const float4 a2 = *(const float4*)&at32[h4 + 2][u4 * 4];
        const float4 a3 = *(const float4*)&at32[h4 + 3][u4 * 4];
        const float* pa0 = (const float*)&a0;
        const float* pa1 = (const float*)&a1;
        const float* pa2 = (const float*)&a2;
        const float* pa3 = (const float*)&a3;
        #pragma unroll
        for (int s = 0; s < 4; ++s) {
            const int u = u4 * 4 + s;
            const float2 vv = *(const float2*)(vrow + (size_t)u * DIN);
            accB[0][0] += pa0[s] * vv.x; accB[0][1] += pa0[s] * vv.y;
            accB[1][0] += pa1[s] * vv.x; accB[1][1] += pa1[s] * vv.y;
            accB[2][0] += pa2[s] * vv.x; accB[2][1] += pa2[s] * vv.y;
            accB[3][0] += pa3[s] * vv.x; accB[3][1] += pa3[s] * vv.y;
        }
    }

    #pragma unroll
    for (int jp = 0; jp < 4; ++jp) {
        float2 st; st.x = accB[jp][0]; st.y = accB[jp][1];
        *(float2*)(part + ((size_t)(b * 4 + j) * 32 + h4 + jp) * 64 + cp * 2) = st;
    }
}

// out[x][c] = sum over j of part[(b*4+j)][h*4+jp][c];  x = h*512 + b*4 + jp
__global__ __launch_bounds__(512) void reduce_kernel(const float* __restrict__ part,
                                                     float* __restrict__ out) {
    const int e = blockIdx.x * 512 + threadIdx.x;   // [0, 262144)
    const int x = e >> 6;
    const int c = e & 63;
    const int h  = x >> 9;
    const int b  = (x >> 2) & 127;
    const int jp = x & 3;
    const int base = (h * 4 + jp) * 64 + c;
    float s = 0.f;
    #pragma unroll
    for (int j = 0; j < 4; ++j)
        s += part[(size_t)(b * 4 + j) * 2048 + base];
    out[e] = s;
}

extern "C" void kernel_launch(void* const* d_in, const int* in_sizes, int n_in,
                              void* d_out, int out_size, void* d_ws, size_t ws_size,
                              hipStream_t stream) {
    const float* v  = (const float*)d_in[0];
    const float* Q  = (const float*)d_in[1];
    const float* Wk = (const float*)d_in[2];
    const float* bk = (const float*)d_in[3];

    float* out  = (float*)d_out;               // 4096*64
    float* attn = out + 4096 * 64;             // 4096*512

    unsigned short* Pgb = (unsigned short*)d_ws;        // 128 KB
    float* qb  = (float*)(Pgb + 4 * 32 * 512);          // 128 f32
    int* flags = (int*)(qb + 128);                      // 128 int
    float* part = (float*)(flags + 128);                // 512*32*64 f32 = 4 MB

    pk_kernel<<<128, 512, 0, stream>>>(Q, Wk, bk, Pgb, qb, flags);
    fused_kernel<<<512, 256, 0, stream>>>(v, Pgb, qb, attn, part, flags);
    reduce_kernel<<<512, 512, 0, stream>>>(part, out);
}

// Round 11
// 56.371 us; speedup vs baseline: 1.5494x; 1.5494x over previous
//
#include <hip/hip_runtime.h>
#include <hip/hip_bf16.h>
#include <math.h>

#define DIN 512
#define TT  512
#define BSZ 128

using bf16x8 = __attribute__((ext_vector_type(8))) short;
using f32x4  = __attribute__((ext_vector_type(4))) float;

static __device__ __forceinline__ unsigned short f2bf(float x) {
    __hip_bfloat16 h = __float2bfloat16(x);
    return *reinterpret_cast<unsigned short*>(&h);
}
static __device__ __forceinline__ unsigned int pack2(float a, float b) {
    return (unsigned int)f2bf(a) | ((unsigned int)f2bf(b) << 16);
}

// ws layout: Pgb bf16 [4 bg][32 p][512 s] (65536 ushort = 128 KB), then qb f32 [128].
// Both pre-scaled by 0.125 (temperature).

__global__ __launch_bounds__(512) void pk_kernel(const float* __restrict__ Q,
                                                 const float* __restrict__ Wk,
                                                 const float* __restrict__ bk,
                                                 unsigned short* __restrict__ Pgb,
                                                 float* __restrict__ qb) {
    const int bid = blockIdx.x;   // [0,128) = bg*32 + p
    const int bg = bid >> 5;
    const int p  = bid & 31;
    const int h  = p >> 2;
    const int ua = p & 3;
    const int a_q = h >> 1;
    const int h_q = (4 * h + bg) & 7;
    const int ch_base = ua * 512 + h * 64;

    __shared__ float qv[64];
    const int tid = threadIdx.x;
    if (tid < 64) qv[tid] = Q[(a_q * 8 + h_q) * 64 + tid];
    __syncthreads();

    const int s = tid;            // 512 threads, one s each
    float acc = 0.f;
    #pragma unroll 8
    for (int d = 0; d < 64; ++d)
        acc += qv[d] * Wk[(size_t)(ch_base + d) * DIN + s];
    Pgb[(size_t)(bg * 32 + p) * 512 + s] = f2bf(acc * 0.125f);

    if (tid == 0) {
        float sum = 0.f;
        for (int d = 0; d < 64; ++d) sum += qv[d] * bk[ch_base + d];
        qb[bg * 32 + p] = sum * 0.125f;
    }
}

// One block per (b, j). scores[128 trow][32 p] = V[128x512] @ P^T via bf16 MFMA.
// 4 waves x (2 M-tiles x 2 N-tiles) of 16x16, K-steps of 32.
__global__ __launch_bounds__(256) void score_kernel(const float* __restrict__ v,
                                                    const unsigned short* __restrict__ Pgb,
                                                    const float* __restrict__ qb,
                                                    float* __restrict__ attn) {
    const int bid = blockIdx.x;   // b*4 + j
    const int b = bid >> 2;
    const int j = bid & 3;
    const int bg = b >> 5;
    const int tid = threadIdx.x;
    const int lane = tid & 63;
    const int w = tid >> 6;       // wave id: M rows w*32..w*32+31

    // LDS: V tile [128 rows][32 k] bf16, row stride 80 B (pad -> conflict-free-at-floor)
    //      P full  [32 p][512 k] bf16, row stride 1040 B
    __shared__ char VtB[128 * 80];          // 10240 B
    __shared__ char PtB[32 * 1040];         // 33280 B
    __shared__ float red2[4][2][4][2];      // [wave][nt][hsub][m,s]

    const float* vbase = v + ((size_t)b * TT + j * 128) * DIN;

    // ---- stage full P (bf16) once: 32 KB ----
    {
        const int p  = tid >> 3;          // [0,32)
        const int sg = tid & 7;           // 64 k (128 B) each
        const uint4* src = (const uint4*)(Pgb + ((size_t)(bg * 32 + p) * 512)) + sg * 8;
        uint4* dst = (uint4*)(PtB + p * 1040 + sg * 128);
        #pragma unroll
        for (int q = 0; q < 8; ++q) dst[q] = src[q];
    }

    const float qv0 = qb[bg * 32 + (lane & 15)];
    const float qv1 = qb[bg * 32 + 16 + (lane & 15)];

    f32x4 acc[2][2];
    #pragma unroll
    for (int i = 0; i < 2; ++i)
        #pragma unroll
        for (int n = 0; n < 2; ++n)
            #pragma unroll
            for (int r = 0; r < 4; ++r) acc[i][n][r] = 0.f;

    // staging assignment: thread = row*2 + half (16 k-values = 64 B f32 each)
    const int srow  = tid >> 1;
    const int shalf = tid & 1;
    const float* vsrc = vbase + (size_t)srow * DIN + shalf * 16;
    char* vdst = VtB + srow * 80 + shalf * 32;

    // A/B frag read offsets
    const int akb = (lane >> 4) * 16;                 // k-chunk byte offset
    const char* aptr = VtB + (w * 32 + (lane & 15)) * 80 + akb;
    const char* bptr0 = PtB + ((lane & 15)) * 1040 + akb;
    const char* bptr1 = PtB + (16 + (lane & 15)) * 1040 + akb;

    // prologue: prefetch k-step 0
    float4 vr[4];
    #pragma unroll
    for (int q = 0; q < 4; ++q) vr[q] = *(const float4*)(vsrc + q * 4);

    for (int kt = 0; kt < 16; ++kt) {
        // pack prefetched f32 -> bf16 and write V tile
        uint4 lo, hi;
        lo.x = pack2(vr[0].x, vr[0].y); lo.y = pack2(vr[0].z, vr[0].w);
        lo.z = pack2(vr[1].x, vr[1].y); lo.w = pack2(vr[1].z, vr[1].w);
        hi.x = pack2(vr[2].x, vr[2].y); hi.y = pack2(vr[2].z, vr[2].w);
        hi.z = pack2(vr[3].x, vr[3].y); hi.w = pack2(vr[3].z, vr[3].w);
        *(uint4*)(vdst)      = lo;
        *(uint4*)(vdst + 16) = hi;
        __syncthreads();

        // prefetch next k-step while MFMAs run
        if (kt < 15) {
            const float* vn = vsrc + (kt + 1) * 32;
            #pragma unroll
            for (int q = 0; q < 4; ++q) vr[q] = *(const float4*)(vn + q * 4);
        }

        const int ksb = kt * 64;   // 32 k * 2 B
        bf16x8 a0 = *(const bf16x8*)(aptr);
        bf16x8 a1 = *(const bf16x8*)(aptr + 16 * 80);
        bf16x8 b0 = *(const bf16x8*)(bptr0 + ksb);
        bf16x8 b1 = *(const bf16x8*)(bptr1 + ksb);
        acc[0][0] = __builtin_amdgcn_mfma_f32_16x16x32_bf16(a0, b0, acc[0][0], 0, 0, 0);
        acc[0][1] = __builtin_amdgcn_mfma_f32_16x16x32_bf16(a0, b1, acc[0][1], 0, 0, 0);
        acc[1][0] = __builtin_amdgcn_mfma_f32_16x16x32_bf16(a1, b0, acc[1][0], 0, 0, 0);
        acc[1][1] = __builtin_amdgcn_mfma_f32_16x16x32_bf16(a1, b1, acc[1][1], 0, 0, 0);
        __syncthreads();
    }

    // ---- logits + per-h softmax ----
    // value acc[i][nt][rr] = score[trow = w*32+i*16+(lane>>4)*4+rr][p = nt*16+(lane&15)]
    float lg[2][8];
    #pragma unroll
    for (int i = 0; i < 2; ++i)
        #pragma unroll
        for (int r = 0; r < 4; ++r) {
            lg[0][i * 4 + r] = acc[i][0][r] + qv0;
            lg[1][i * 4 + r] = acc[i][1][r] + qv1;
        }

    const int hsub = (lane >> 2) & 3;
    float mw[2], sw[2], ev[2][8];
    #pragma unroll
    for (int nt = 0; nt < 2; ++nt) {
        float m = lg[nt][0];
        #pragma unroll
        for (int q = 1; q < 8; ++q) m = fmaxf(m, lg[nt][q]);
        m = fmaxf(m, __shfl_xor(m, 1));
        m = fmaxf(m, __shfl_xor(m, 2));
        m = fmaxf(m, __shfl_xor(m, 16));
        m = fmaxf(m, __shfl_xor(m, 32));
        float s = 0.f;
        #pragma unroll
        for (int q = 0; q < 8; ++q) { ev[nt][q] = __expf(lg[nt][q] - m); s += ev[nt][q]; }
        s += __shfl_xor(s, 1);
        s += __shfl_xor(s, 2);
        s += __shfl_xor(s, 16);
        s += __shfl_xor(s, 32);
        mw[nt] = m; sw[nt] = s;
    }
    if ((lane & 0x33) == 0) {   // lanes 0,4,8,12: one per hsub
        #pragma unroll
        for (int nt = 0; nt < 2; ++nt) {
            red2[w][nt][hsub][0] = mw[nt];
            red2[w][nt][hsub][1] = sw[nt];
        }
    }
    __syncthreads();

    #pragma unroll
    for (int nt = 0; nt < 2; ++nt) {
        float M = red2[0][nt][hsub][0];
        M = fmaxf(M, red2[1][nt][hsub][0]);
        M = fmaxf(M, red2[2][nt][hsub][0]);
        M = fmaxf(M, red2[3][nt][hsub][0]);
        float S = 0.f;
        #pragma unroll
        for (int w2 = 0; w2 < 4; ++w2)
            S += __expf(red2[w2][nt][hsub][0] - M) * red2[w2][nt][hsub][1];
        const float factor = __expf(mw[nt] - M) / S;

        const int h = nt * 4 + hsub;
        float* arow = attn + ((size_t)(h * 512 + b * 4 + j)) * 512;
        const int ua = lane & 3;
        #pragma unroll
        for (int i = 0; i < 2; ++i)
            #pragma unroll
            for (int r = 0; r < 4; ++r) {
                const int trow = w * 32 + i * 16 + ((lane >> 4) & 3) * 4 + r;
                arow[trow * 4 + ua] = ev[nt][i * 4 + r] * factor;
            }
    }
}

// One block per (b, h): out[x=(h,b,j)][c] = sum_u attn[x][u] * v[b,u,h*64+c]
__global__ __launch_bounds__(256) void pv_kernel(const float* __restrict__ v,
                                                 const float* __restrict__ attn,
                                                 float* __restrict__ out) {
    const int bid = blockIdx.x;   // b*8 + h
    const int b = bid >> 3;
    const int h = bid & 7;
    const int tid = threadIdx.x;

    __shared__ float at[4][512];
    __shared__ float red[32][4][68];   // [up][j][c], padded row

    {   // stage attn rows for 4 j values (8 KB, coalesced)
        const int j  = tid >> 6;
        const int u8 = (tid & 63) * 8;
        const float* src = attn + ((size_t)(h * 512 + b * 4 + j)) * 512 + u8;
        *(float4*)&at[j][u8]     = *(const float4*)(src);
        *(float4*)&at[j][u8 + 4] = *(const float4*)(src + 4);
    }
    __syncthreads();

    const int cg = tid & 7;          // channel octet: c8 = cg*8
    const int up = tid >> 3;         // u phase [0,32)
    const int c8 = cg * 8;
    const float* vb = v + (size_t)b * TT * DIN + h * 64 + c8;

    float acc[4][8];
    #pragma unroll
    for (int jj = 0; jj < 4; ++jj)
        #pragma unroll
        for (int ci = 0; ci < 8; ++ci) acc[jj][ci] = 0.f;

    // prologue prefetch u = up
    const float* pcur = vb + (size_t)up * DIN;
    float4 r0 = *(const float4*)(pcur);
    float4 r1 = *(const float4*)(pcur + 4);

    for (int it = 0; it < 16; ++it) {
        const int u = it * 32 + up;
        const float4 c0 = r0;
        const float4 c1 = r1;
        if (it < 15) {
            const float* pn = vb + (size_t)(u + 32) * DIN;
            r0 = *(const float4*)(pn);
            r1 = *(const float4*)(pn + 4);
        }
        const float a0 = at[0][u];
        const float a1 = at[1][u];
        const float a2 = at[2][u];
        const float a3 = at[3][u];
        acc[0][0] += a0 * c0.x; acc[0][1] += a0 * c0.y; acc[0][2] += a0 * c0.z; acc[0][3] += a0 * c0.w;
        acc[0][4] += a0 * c1.x; acc[0][5] += a0 * c1.y; acc[0][6] += a0 * c1.z; acc[0][7] += a0 * c1.w;
        acc[1][0] += a1 * c0.x; acc[1][1] += a1 * c0.y; acc[1][2] += a1 * c0.z; acc[1][3] += a1 * c0.w;
        acc[1][4] += a1 * c1.x; acc[1][5] += a1 * c1.y; acc[1][6] += a1 * c1.z; acc[1][7] += a1 * c1.w;
        acc[2][0] += a2 * c0.x; acc[2][1] += a2 * c0.y; acc[2][2] += a2 * c0.z; acc[2][3] += a2 * c0.w;
        acc[2][4] += a2 * c1.x; acc[2][5] += a2 * c1.y; acc[2][6] += a2 * c1.z; acc[2][7] += a2 * c1.w;
        acc[3][0] += a3 * c0.x; acc[3][1] += a3 * c0.y; acc[3][2] += a3 * c0.z; acc[3][3] += a3 * c0.w;
        acc[3][4] += a3 * c1.x; acc[3][5] += a3 * c1.y; acc[3][6] += a3 * c1.z; acc[3][7] += a3 * c1.w;
    }

    #pragma unroll
    for (int jj = 0; jj < 4; ++jj) {
        float4 w0, w1;
        w0.x = acc[jj][0]; w0.y = acc[jj][1]; w0.z = acc[jj][2]; w0.w = acc[jj][3];
        w1.x = acc[jj][4]; w1.y = acc[jj][5]; w1.z = acc[jj][6]; w1.w = acc[jj][7];
        *(float4*)&red[up][jj][c8]     = w0;
        *(float4*)&red[up][jj][c8 + 4] = w1;
    }
    __syncthreads();

    const int jo = tid >> 6;
    const int c  = tid & 63;
    float s = 0.f;
    #pragma unroll
    for (int r2 = 0; r2 < 32; ++r2) s += red[r2][jo][c];
    out[((size_t)(h * 512 + b * 4 + jo)) * 64 + c] = s;
}

extern "C" void kernel_launch(void* const* d_in, const int* in_sizes, int n_in,
                              void* d_out, int out_size, void* d_ws, size_t ws_size,
                              hipStream_t stream) {
    const float* v  = (const float*)d_in[0];
    const float* Q  = (const float*)d_in[1];
    const float* Wk = (const float*)d_in[2];
    const float* bk = (const float*)d_in[3];

    float* out  = (float*)d_out;               // 4096*64
    float* attn = out + 4096 * 64;             // 4096*512

    unsigned short* Pgb = (unsigned short*)d_ws;     // 4*32*512 bf16
    float* qb = (float*)(Pgb + 4 * 32 * 512);        // 128 f32

    pk_kernel<<<128, 512, 0, stream>>>(Q, Wk, bk, Pgb, qb);
    score_kernel<<<512, 256, 0, stream>>>(v, Pgb, qb, attn);
    pv_kernel<<<1024, 256, 0, stream>>>(v, attn, out);
}